// Round 1
// baseline (559.819 us; speedup 1.0000x reference)
//
#include <hip/hip_runtime.h>
#include <stdint.h>

// Problem: y[8192,4096] = x[8192,4096] @ W[4096,4096]^T + bias,
// W reconstructed from codebook[4096,8] gathered by indices[2M].
// Strategy: dequant W -> bf16 (ws), convert x -> bf16 (ws), then
// m97-style bf16 MFMA GEMM (128x128 tile, BK=32, global_load_lds width-16).

#define M_DIM 8192
#define N_DIM 4096
#define K_DIM 4096
#define BM 128
#define BN 128
#define BK 32
#define NUM_W_BLOCKS 2097152   // 4096*4096/8

typedef __attribute__((ext_vector_type(8))) __bf16 bf16x8;
typedef __attribute__((ext_vector_type(4))) float floatx4;

// fp32 -> bf16 round-to-nearest-even (finite inputs)
__device__ __forceinline__ unsigned int f2bf(float f) {
    unsigned int u = __builtin_bit_cast(unsigned int, f);
    u += 0x7fffu + ((u >> 16) & 1u);
    return u >> 16;
}

// ---------------- W reconstruction: codebook gather -> bf16 ----------------
__global__ __launch_bounds__(256) void build_w_kernel(
    const float* __restrict__ cb, const int* __restrict__ idx,
    uint4* __restrict__ W) {
    const int b = blockIdx.x * 256 + threadIdx.x;   // one 8-elem block per thread
    const int id = idx[b];
    const float4* s = (const float4*)(cb + ((size_t)id << 3));
    const float4 a = s[0];
    const float4 c = s[1];
    uint4 o;
    o.x = f2bf(a.x) | (f2bf(a.y) << 16);
    o.y = f2bf(a.z) | (f2bf(a.w) << 16);
    o.z = f2bf(c.x) | (f2bf(c.y) << 16);
    o.w = f2bf(c.z) | (f2bf(c.w) << 16);
    W[b] = o;
}

// ---------------- x: fp32 -> bf16 ----------------
__global__ __launch_bounds__(256) void cvt_x_kernel(
    const float4* __restrict__ x, uint4* __restrict__ xb) {
    const int t = blockIdx.x * 256 + threadIdx.x;   // 8 floats per thread
    const float4 a = x[2 * t];
    const float4 c = x[2 * t + 1];
    uint4 o;
    o.x = f2bf(a.x) | (f2bf(a.y) << 16);
    o.y = f2bf(a.z) | (f2bf(a.w) << 16);
    o.z = f2bf(c.x) | (f2bf(c.y) << 16);
    o.w = f2bf(c.z) | (f2bf(c.w) << 16);
    xb[t] = o;
}

// ---------------- async global -> LDS, 16B per lane ----------------
__device__ __forceinline__ void async_copy16(const void* g, void* s) {
    __builtin_amdgcn_global_load_lds(
        (const __attribute__((address_space(1))) unsigned int*)(uintptr_t)g,
        (__attribute__((address_space(3))) unsigned int*)(uintptr_t)s,
        16, 0, 0);
}

// ---------------- GEMM: C[M][N] = A[M][K] * B[N][K]^T + bias ----------------
// 256 threads = 4 waves in 2x2 grid; each wave: 4x4 tiles of 16x16x32 MFMA.
__global__ __launch_bounds__(256) void gemm_bt_kernel(
    const __bf16* __restrict__ A,   // [M][K] bf16
    const __bf16* __restrict__ B,   // [N][K] bf16
    const float* __restrict__ bias, // [N]
    float* __restrict__ C) {        // [M][N] fp32
    __shared__ __align__(16) __bf16 sA[BM * BK];
    __shared__ __align__(16) __bf16 sB[BN * BK];

    const int tid = threadIdx.x;
    const int wave = tid >> 6;
    const int lane = tid & 63;

    const int m0 = blockIdx.x * BM;
    const int n0 = blockIdx.y * BN;

    const int wm = (wave >> 1) * 64;   // wave's m offset in tile
    const int wn = (wave & 1) * 64;    // wave's n offset in tile

    // MFMA fragment addressing (16x16x32 bf16):
    // A frag: lane holds A[m = lane&15][k = (lane>>4)*8 + j], j=0..7
    // B frag: lane holds B[n = lane&15][k = (lane>>4)*8 + j]  (B^T layout)
    const int fr = lane & 15;
    const int fk = (lane >> 4) * 8;

    // staging: thread t loads 16B: row = t>>2 (0..63), col = (t&3)*8 bf16
    const int srow = tid >> 2;
    const int scol = (tid & 3) * 8;

    const __bf16* gA = A + (size_t)(m0 + srow) * K_DIM + scol;
    const __bf16* gB = B + (size_t)(n0 + srow) * K_DIM + scol;
    // per-wave LDS chunk bases (wave-uniform; lanes land at base + lane*16B)
    __bf16* sAw = sA + wave * 512;
    __bf16* sBw = sB + wave * 512;

    floatx4 acc[4][4] = {};

    for (int k0 = 0; k0 < K_DIM; k0 += BK) {
        async_copy16(gA + k0, sAw);                            // rows 0..63
        async_copy16(gA + k0 + (size_t)64 * K_DIM, sAw + 2048); // rows 64..127
        async_copy16(gB + k0, sBw);
        async_copy16(gB + k0 + (size_t)64 * K_DIM, sBw + 2048);
        __syncthreads();

        bf16x8 af[4], bfr[4];
#pragma unroll
        for (int i = 0; i < 4; ++i)
            af[i] = *(const bf16x8*)(sA + (wm + i * 16 + fr) * BK + fk);
#pragma unroll
        for (int j = 0; j < 4; ++j)
            bfr[j] = *(const bf16x8*)(sB + (wn + j * 16 + fr) * BK + fk);

#pragma unroll
        for (int i = 0; i < 4; ++i)
#pragma unroll
            for (int j = 0; j < 4; ++j)
                acc[i][j] = __builtin_amdgcn_mfma_f32_16x16x32_bf16(
                    af[i], bfr[j], acc[i][j], 0, 0, 0);
        __syncthreads();
    }

    // Epilogue. C/D layout: col = lane&15, row = (lane>>4)*4 + reg
    const int crow = (lane >> 4) * 4;
    const int ccol = lane & 15;
#pragma unroll
    for (int j = 0; j < 4; ++j) {
        const int n = n0 + wn + j * 16 + ccol;
        const float bv = bias[n];
#pragma unroll
        for (int i = 0; i < 4; ++i) {
            const int m = m0 + wm + i * 16 + crow;
            float* cp = C + (size_t)m * N_DIM + n;
#pragma unroll
            for (int r = 0; r < 4; ++r)
                cp[(size_t)r * N_DIM] = acc[i][j][r] + bv;
        }
    }
}

extern "C" void kernel_launch(void* const* d_in, const int* in_sizes, int n_in,
                              void* d_out, int out_size, void* d_ws, size_t ws_size,
                              hipStream_t stream) {
    const float* x    = (const float*)d_in[0];   // [4,2048,4096] fp32
    const float* cb   = (const float*)d_in[1];   // [4096,8] fp32
    const int*   idx  = (const int*)d_in[2];     // [2M]
    const float* bias = (const float*)d_in[3];   // [4096]
    float* out = (float*)d_out;                  // [4,2048,4096] fp32

    // workspace layout: W_bf16 (32 MB) | x_bf16 (64 MB)
    __bf16* Wb = (__bf16*)d_ws;
    __bf16* Xb = (__bf16*)((char*)d_ws + (size_t)N_DIM * K_DIM * sizeof(__bf16));

    build_w_kernel<<<NUM_W_BLOCKS / 256, 256, 0, stream>>>(cb, idx, (uint4*)Wb);
    cvt_x_kernel<<<(M_DIM * K_DIM / 8) / 256, 256, 0, stream>>>(
        (const float4*)x, (uint4*)Xb);

    dim3 grid(M_DIM / BM, N_DIM / BN);
    gemm_bt_kernel<<<grid, 256, 0, stream>>>(Xb, Wb, bias, out);
}

// Round 2
// 550.801 us; speedup vs baseline: 1.0164x; 1.0164x over previous
//
#include <hip/hip_runtime.h>
#include <stdint.h>

// y[8192,4096] = x[8192,4096] @ W[4096,4096]^T + bias
// W from codebook[4096,8] gathered by indices[2M].
// R2: fused prep (dequant W + cvt x) in one dispatch; nt C stores.

#define M_DIM 8192
#define N_DIM 4096
#define K_DIM 4096
#define BM 128
#define BN 128
#define BK 32
#define NUM_W_BLOCKS 2097152   // 4096*4096/8
#define W_WGS (NUM_W_BLOCKS / 256)            // 8192 workgroups for W part
#define X_THREADS (M_DIM * K_DIM / 16)        // 2M threads, 16 floats each
#define X_WGS (X_THREADS / 256)               // 8192 workgroups for x part

typedef __attribute__((ext_vector_type(8))) __bf16 bf16x8;
typedef __attribute__((ext_vector_type(4))) float floatx4;

// fp32 -> bf16 round-to-nearest-even (finite inputs)
__device__ __forceinline__ unsigned int f2bf(float f) {
    unsigned int u = __builtin_bit_cast(unsigned int, f);
    u += 0x7fffu + ((u >> 16) & 1u);
    return u >> 16;
}

__device__ __forceinline__ uint4 pack8(float4 a, float4 c) {
    uint4 o;
    o.x = f2bf(a.x) | (f2bf(a.y) << 16);
    o.y = f2bf(a.z) | (f2bf(a.w) << 16);
    o.z = f2bf(c.x) | (f2bf(c.y) << 16);
    o.w = f2bf(c.z) | (f2bf(c.w) << 16);
    return o;
}

// ------------- fused prep: W dequant-gather + x fp32->bf16 -------------
// WGs [0, W_WGS): one codebook block (8 elems) per thread.
// WGs [W_WGS, W_WGS+X_WGS): 16 floats of x per thread (64B load / 32B store).
__global__ __launch_bounds__(256) void prep_kernel(
    const float* __restrict__ cb, const int* __restrict__ idx,
    uint4* __restrict__ W, const float4* __restrict__ x,
    uint4* __restrict__ xb) {
    const int wg = blockIdx.x;
    if (wg < W_WGS) {
        const int b = wg * 256 + threadIdx.x;
        const int id = idx[b];
        const float4* s = (const float4*)(cb + ((size_t)id << 3));
        W[b] = pack8(s[0], s[1]);
    } else {
        const size_t t = (size_t)(wg - W_WGS) * 256 + threadIdx.x;
        const float4* src = x + 4 * t;
        const float4 a = src[0], b = src[1], c = src[2], d = src[3];
        uint4* dst = xb + 2 * t;
        dst[0] = pack8(a, b);
        dst[1] = pack8(c, d);
    }
}

// ---------------- async global -> LDS, 16B per lane ----------------
__device__ __forceinline__ void async_copy16(const void* g, void* s) {
    __builtin_amdgcn_global_load_lds(
        (const __attribute__((address_space(1))) unsigned int*)(uintptr_t)g,
        (__attribute__((address_space(3))) unsigned int*)(uintptr_t)s,
        16, 0, 0);
}

// ---------------- GEMM: C[M][N] = A[M][K] * B[N][K]^T + bias ----------------
// 256 threads = 4 waves in 2x2 grid; each wave: 4x4 tiles of 16x16x32 MFMA.
__global__ __launch_bounds__(256) void gemm_bt_kernel(
    const __bf16* __restrict__ A,   // [M][K] bf16
    const __bf16* __restrict__ B,   // [N][K] bf16
    const float* __restrict__ bias, // [N]
    float* __restrict__ C) {        // [M][N] fp32
    __shared__ __align__(16) __bf16 sA[BM * BK];
    __shared__ __align__(16) __bf16 sB[BN * BK];

    const int tid = threadIdx.x;
    const int wave = tid >> 6;
    const int lane = tid & 63;

    const int m0 = blockIdx.x * BM;
    const int n0 = blockIdx.y * BN;

    const int wm = (wave >> 1) * 64;   // wave's m offset in tile
    const int wn = (wave & 1) * 64;    // wave's n offset in tile

    // A frag: lane holds A[m = lane&15][k = (lane>>4)*8 + j], j=0..7
    // B frag: lane holds B[n = lane&15][k = (lane>>4)*8 + j]  (B^T layout)
    const int fr = lane & 15;
    const int fk = (lane >> 4) * 8;

    // staging: thread t loads 16B: row = t>>2 (0..63), col = (t&3)*8 bf16
    const int srow = tid >> 2;
    const int scol = (tid & 3) * 8;

    const __bf16* gA = A + (size_t)(m0 + srow) * K_DIM + scol;
    const __bf16* gB = B + (size_t)(n0 + srow) * K_DIM + scol;
    __bf16* sAw = sA + wave * 512;   // wave-uniform LDS base
    __bf16* sBw = sB + wave * 512;

    floatx4 acc[4][4] = {};

    for (int k0 = 0; k0 < K_DIM; k0 += BK) {
        async_copy16(gA + k0, sAw);                             // rows 0..63
        async_copy16(gA + k0 + (size_t)64 * K_DIM, sAw + 2048); // rows 64..127
        async_copy16(gB + k0, sBw);
        async_copy16(gB + k0 + (size_t)64 * K_DIM, sBw + 2048);
        __syncthreads();

        bf16x8 af[4], bfr[4];
#pragma unroll
        for (int i = 0; i < 4; ++i)
            af[i] = *(const bf16x8*)(sA + (wm + i * 16 + fr) * BK + fk);
#pragma unroll
        for (int j = 0; j < 4; ++j)
            bfr[j] = *(const bf16x8*)(sB + (wn + j * 16 + fr) * BK + fk);

#pragma unroll
        for (int i = 0; i < 4; ++i)
#pragma unroll
            for (int j = 0; j < 4; ++j)
                acc[i][j] = __builtin_amdgcn_mfma_f32_16x16x32_bf16(
                    af[i], bfr[j], acc[i][j], 0, 0, 0);
        __syncthreads();
    }

    // Epilogue. C/D layout: col = lane&15, row = (lane>>4)*4 + reg
    const int crow = (lane >> 4) * 4;
    const int ccol = lane & 15;
#pragma unroll
    for (int j = 0; j < 4; ++j) {
        const int n = n0 + wn + j * 16 + ccol;
        const float bv = bias[n];
#pragma unroll
        for (int i = 0; i < 4; ++i) {
            const int m = m0 + wm + i * 16 + crow;
            float* cp = C + (size_t)m * N_DIM + n;
#pragma unroll
            for (int r = 0; r < 4; ++r)
                __builtin_nontemporal_store(acc[i][j][r] + bv,
                                            cp + (size_t)r * N_DIM);
        }
    }
}

extern "C" void kernel_launch(void* const* d_in, const int* in_sizes, int n_in,
                              void* d_out, int out_size, void* d_ws, size_t ws_size,
                              hipStream_t stream) {
    const float* x    = (const float*)d_in[0];   // [4,2048,4096] fp32
    const float* cb   = (const float*)d_in[1];   // [4096,8] fp32
    const int*   idx  = (const int*)d_in[2];     // [2M]
    const float* bias = (const float*)d_in[3];   // [4096]
    float* out = (float*)d_out;                  // [4,2048,4096] fp32

    // workspace layout: W_bf16 (32 MB) | x_bf16 (64 MB)
    __bf16* Wb = (__bf16*)d_ws;
    __bf16* Xb = (__bf16*)((char*)d_ws + (size_t)N_DIM * K_DIM * sizeof(__bf16));

    prep_kernel<<<W_WGS + X_WGS, 256, 0, stream>>>(
        cb, idx, (uint4*)Wb, (const float4*)x, (uint4*)Xb);

    dim3 grid(M_DIM / BM, N_DIM / BN);
    gemm_bt_kernel<<<grid, 256, 0, stream>>>(Xb, Wb, bias, out);
}

// Round 4
// 528.950 us; speedup vs baseline: 1.0584x; 1.0413x over previous
//
#include <hip/hip_runtime.h>
#include <stdint.h>

// y[8192,4096] = x[8192,4096] @ W[4096,4096]^T + bias
// W from codebook[4096,8] gathered by indices[2M].
// R4: R3 (XOR-swizzled LDS, coalesced prep) with nt-load compile fix
//     (clang ext_vector float4 instead of HIP_vector_type).

#define M_DIM 8192
#define N_DIM 4096
#define K_DIM 4096
#define BM 128
#define BN 128
#define BK 32
#define NUM_W_BLOCKS 2097152                  // 4096*4096/8
#define W_WGS (NUM_W_BLOCKS / 256)            // 8192 WGs for W dequant
#define X_WGS ((M_DIM * K_DIM / 4) / 256)     // 32768 WGs, one float4/thread

typedef __attribute__((ext_vector_type(8))) __bf16 bf16x8;
typedef __attribute__((ext_vector_type(4))) float floatx4;
typedef __attribute__((ext_vector_type(2))) unsigned int uintx2;

// fp32 -> bf16 round-to-nearest-even (finite inputs)
__device__ __forceinline__ unsigned int f2bf(float f) {
    unsigned int u = __builtin_bit_cast(unsigned int, f);
    u += 0x7fffu + ((u >> 16) & 1u);
    return u >> 16;
}

// ------------- fused prep: W dequant-gather + x fp32->bf16 -------------
// WGs [0, W_WGS): one codebook block (8 elems) per thread.
// WGs [W_WGS, W_WGS+X_WGS): one float4 per thread (16B load / 8B store).
__global__ __launch_bounds__(256) void prep_kernel(
    const float* __restrict__ cb, const int* __restrict__ idx,
    uint4* __restrict__ W, const floatx4* __restrict__ x,
    uintx2* __restrict__ xb) {
    const int wg = blockIdx.x;
    if (wg < W_WGS) {
        const int b = wg * 256 + threadIdx.x;
        const int id = __builtin_nontemporal_load(idx + b);
        const float4* s = (const float4*)(cb + ((size_t)id << 3));
        const float4 a = s[0];
        const float4 c = s[1];
        uint4 o;
        o.x = f2bf(a.x) | (f2bf(a.y) << 16);
        o.y = f2bf(a.z) | (f2bf(a.w) << 16);
        o.z = f2bf(c.x) | (f2bf(c.y) << 16);
        o.w = f2bf(c.z) | (f2bf(c.w) << 16);
        W[b] = o;
    } else {
        const size_t t = (size_t)(wg - W_WGS) * 256 + threadIdx.x;
        const floatx4 a = __builtin_nontemporal_load(x + t);
        uintx2 o;
        o.x = f2bf(a.x) | (f2bf(a.y) << 16);
        o.y = f2bf(a.z) | (f2bf(a.w) << 16);
        xb[t] = o;
    }
}

// ---------------- async global -> LDS, 16B per lane ----------------
__device__ __forceinline__ void async_copy16(const void* g, void* s) {
    __builtin_amdgcn_global_load_lds(
        (const __attribute__((address_space(1))) unsigned int*)(uintptr_t)g,
        (__attribute__((address_space(3))) unsigned int*)(uintptr_t)s,
        16, 0, 0);
}

// ---------------- GEMM: C[M][N] = A[M][K] * B[N][K]^T + bias ----------------
// 256 threads = 4 waves in 2x2 grid; each wave: 4x4 tiles of 16x16x32 MFMA.
// LDS layout swizzle: row r, logical 16B k-chunk c stored at physical chunk
// p = c ^ ((r>>1)&3).  (r>>1)&3 is invariant under r+=16 / r+=64, so one
// swizzle term serves all fragment rows and both staging halves.
__global__ __launch_bounds__(256) void gemm_bt_kernel(
    const __bf16* __restrict__ A,   // [M][K] bf16
    const __bf16* __restrict__ B,   // [N][K] bf16
    const float* __restrict__ bias, // [N]
    float* __restrict__ C) {        // [M][N] fp32
    __shared__ __align__(16) __bf16 sA[BM * BK];
    __shared__ __align__(16) __bf16 sB[BN * BK];

    const int tid = threadIdx.x;
    const int wave = tid >> 6;
    const int lane = tid & 63;

    const int m0 = blockIdx.x * BM;
    const int n0 = blockIdx.y * BN;

    const int wm = (wave >> 1) * 64;   // wave's m offset in tile
    const int wn = (wave & 1) * 64;    // wave's n offset in tile

    // A frag (logical): lane holds A[m = lane&15][k = (lane>>4)*8 + j], j=0..7
    const int fr = lane & 15;
    // physical chunk for this lane's fragment read (swizzled)
    const int sw = (((lane >> 4) ^ ((fr >> 1) & 3)) * 8);

    // staging: thread t owns physical LDS 16B slot (row = t>>2, p = t&3);
    // it must fetch logical chunk c = p ^ ((row>>1)&3) of that row.
    const int srow = tid >> 2;                      // 0..63
    const int scol = ((tid & 3) ^ ((srow >> 1) & 3)) * 8;

    const __bf16* gA = A + (size_t)(m0 + srow) * K_DIM + scol;
    const __bf16* gB = B + (size_t)(n0 + srow) * K_DIM + scol;
    __bf16* sAw = sA + wave * 512;   // wave-uniform LDS base (lane*16B dest)
    __bf16* sBw = sB + wave * 512;

    floatx4 acc[4][4] = {};

    for (int k0 = 0; k0 < K_DIM; k0 += BK) {
        async_copy16(gA + k0, sAw);                             // rows 0..63
        async_copy16(gA + k0 + (size_t)64 * K_DIM, sAw + 2048); // rows 64..127
        async_copy16(gB + k0, sBw);
        async_copy16(gB + k0 + (size_t)64 * K_DIM, sBw + 2048);
        __syncthreads();

        bf16x8 af[4], bfr[4];
#pragma unroll
        for (int i = 0; i < 4; ++i)
            af[i] = *(const bf16x8*)(sA + (wm + i * 16 + fr) * BK + sw);
#pragma unroll
        for (int j = 0; j < 4; ++j)
            bfr[j] = *(const bf16x8*)(sB + (wn + j * 16 + fr) * BK + sw);

#pragma unroll
        for (int i = 0; i < 4; ++i)
#pragma unroll
            for (int j = 0; j < 4; ++j)
                acc[i][j] = __builtin_amdgcn_mfma_f32_16x16x32_bf16(
                    af[i], bfr[j], acc[i][j], 0, 0, 0);
        __syncthreads();
    }

    // Epilogue. C/D layout: col = lane&15, row = (lane>>4)*4 + reg
    const int crow = (lane >> 4) * 4;
    const int ccol = lane & 15;
#pragma unroll
    for (int j = 0; j < 4; ++j) {
        const int n = n0 + wn + j * 16 + ccol;
        const float bv = bias[n];
#pragma unroll
        for (int i = 0; i < 4; ++i) {
            const int m = m0 + wm + i * 16 + crow;
            float* cp = C + (size_t)m * N_DIM + n;
#pragma unroll
            for (int r = 0; r < 4; ++r)
                __builtin_nontemporal_store(acc[i][j][r] + bv,
                                            cp + (size_t)r * N_DIM);
        }
    }
}

extern "C" void kernel_launch(void* const* d_in, const int* in_sizes, int n_in,
                              void* d_out, int out_size, void* d_ws, size_t ws_size,
                              hipStream_t stream) {
    const float* x    = (const float*)d_in[0];   // [4,2048,4096] fp32
    const float* cb   = (const float*)d_in[1];   // [4096,8] fp32
    const int*   idx  = (const int*)d_in[2];     // [2M]
    const float* bias = (const float*)d_in[3];   // [4096]
    float* out = (float*)d_out;                  // [4,2048,4096] fp32

    // workspace layout: W_bf16 (32 MB) | x_bf16 (64 MB)
    __bf16* Wb = (__bf16*)d_ws;
    __bf16* Xb = (__bf16*)((char*)d_ws + (size_t)N_DIM * K_DIM * sizeof(__bf16));

    prep_kernel<<<W_WGS + X_WGS, 256, 0, stream>>>(
        cb, idx, (uint4*)Wb, (const floatx4*)x, (uintx2*)Xb);

    dim3 grid(M_DIM / BM, N_DIM / BN);
    gemm_bt_kernel<<<grid, 256, 0, stream>>>(Xb, Wb, bias, out);
}